// Round 9
// baseline (11113.782 us; speedup 1.0000x reference)
//
#include <hip/hip_runtime.h>
#include <cstdint>
#include <cstddef>

#define BATCH 8
#define SEQ   256
#define HID   1024
#define GATES 4096   // 4*HID
#define VOC   32000

typedef __attribute__((ext_vector_type(8))) short bf16x8;
typedef __attribute__((ext_vector_type(4))) float f32x4;

// ---------- helpers ----------
__device__ __forceinline__ float sigf(float x){ return 1.0f/(1.0f + __expf(-x)); }
__device__ __forceinline__ float tanhf_(float x){ return 1.0f - 2.0f/(__expf(2.0f*x) + 1.0f); }

__device__ __forceinline__ unsigned short f2bf(float x){
  union { float f; unsigned u; } v; v.f = x;
  unsigned r = v.u + 0x7fffu + ((v.u >> 16) & 1u);
  return (unsigned short)(r >> 16);
}
__device__ __forceinline__ float bf2f(unsigned short h){
  union { float f; unsigned u; } v; v.u = ((unsigned)h) << 16; return v.f;
}

// ---------- init: zero {h,epoch} pair buffers ----------
// hb2: 2 layers x [2][8][1024] x {f32,u32} = 32768 ulonglongs
__global__ void k_init(unsigned long long* __restrict__ hb2){
  int tid = blockIdx.x*blockDim.x + threadIdx.x;
  int nt = gridDim.x*blockDim.x;
  for (int i = tid; i < 2*2*BATCH*HID; i += nt) hb2[i] = 0ull;
}

// ---------- Wh transpose: WhT[l][n][k] = Wh[l][k][n] ----------
__global__ void k_transpose(const float* __restrict__ Wh, float* __restrict__ WhT){
  __shared__ float tile[32][33];
  int l = blockIdx.z;
  int n0 = blockIdx.x*32, k0 = blockIdx.y*32;
  const float* src = Wh  + (size_t)l*HID*GATES;
  float*       dst = WhT + (size_t)l*GATES*HID;
  int tx = threadIdx.x, ty = threadIdx.y;
  #pragma unroll
  for (int i=0;i<4;i++)
    tile[ty+i*8][tx] = src[(size_t)(k0+ty+i*8)*GATES + n0 + tx];
  __syncthreads();
  #pragma unroll
  for (int i=0;i<4;i++)
    dst[(size_t)(n0+ty+i*8)*HID + k0 + tx] = tile[tx][ty+i*8];
}

// ---------- f32 GEMM (pre-gate GEMMs only) ----------
template<int AMODE>
__global__ __launch_bounds__(256) void k_gemm(
    const float* __restrict__ A,
    const float* __restrict__ W,     // [1024][N] row-major
    const float* __restrict__ b1,
    const float* __restrict__ b2,
    const int*   __restrict__ tokens,
    const float* __restrict__ emb,
    float* __restrict__ C, int N)
{
  __shared__ float As[16*132];
  __shared__ float Bs[16*128];
  int tid = threadIdx.x;
  int m0 = blockIdx.y*128, n0 = blockIdx.x*128;

  int arow = tid >> 1;
  int akq  = (tid & 1) * 8;
  const float* aptr;
  { int gm = m0 + arow;
    if (AMODE==1){ int tt = gm>>3, bb = gm&7; aptr = emb + (size_t)tokens[bb*SEQ+tt]*1024; }
    else          aptr = A + (size_t)gm*1024; }

  int bk = tid >> 5;
  int bn = (tid & 31) * 4;
  const float* wptr = W + (size_t)bk*N + n0 + bn;

  int tx = tid & 15, ty = tid >> 4;
  float acc[8][8];
  #pragma unroll
  for (int i=0;i<8;i++){
    #pragma unroll
    for (int j=0;j<8;j++) acc[i][j] = 0.0f;
  }

  for (int k0=0;k0<1024;k0+=16){
    float4 av0 = *(const float4*)(aptr + k0 + akq);
    float4 av1 = *(const float4*)(aptr + k0 + akq + 4);
    float4 wv0 = *(const float4*)(wptr + (size_t)k0*N);
    float4 wv1 = *(const float4*)(wptr + (size_t)(k0+8)*N);
    __syncthreads();
    As[(akq+0)*132 + arow] = av0.x;
    As[(akq+1)*132 + arow] = av0.y;
    As[(akq+2)*132 + arow] = av0.z;
    As[(akq+3)*132 + arow] = av0.w;
    As[(akq+4)*132 + arow] = av1.x;
    As[(akq+5)*132 + arow] = av1.y;
    As[(akq+6)*132 + arow] = av1.z;
    As[(akq+7)*132 + arow] = av1.w;
    *(float4*)&Bs[bk*128 + bn]     = wv0;
    *(float4*)&Bs[(bk+8)*128 + bn] = wv1;
    __syncthreads();
    #pragma unroll
    for (int k=0;k<16;k++){
      float ra[8], rb[8];
      *(float4*)&ra[0] = *(float4*)&As[k*132 + ty*8];
      *(float4*)&ra[4] = *(float4*)&As[k*132 + ty*8 + 4];
      *(float4*)&rb[0] = *(float4*)&Bs[k*128 + tx*8];
      *(float4*)&rb[4] = *(float4*)&Bs[k*128 + tx*8 + 4];
      #pragma unroll
      for (int i=0;i<8;i++){
        #pragma unroll
        for (int j=0;j<8;j++)
          acc[i][j] = fmaf(ra[i], rb[j], acc[i][j]);
      }
    }
  }

  float bias[8];
  { int nb = n0 + tx*8;
    *(float4*)&bias[0] = *(const float4*)(b1 + nb);
    *(float4*)&bias[4] = *(const float4*)(b1 + nb + 4);
    if (b2){
      float4 c0 = *(const float4*)(b2 + nb);
      float4 c1 = *(const float4*)(b2 + nb + 4);
      bias[0]+=c0.x; bias[1]+=c0.y; bias[2]+=c0.z; bias[3]+=c0.w;
      bias[4]+=c1.x; bias[5]+=c1.y; bias[6]+=c1.z; bias[7]+=c1.w;
    }
  }
  #pragma unroll
  for (int i=0;i<8;i++){
    int gm = m0 + ty*8 + i;
    float* crow = C + (size_t)gm*N;
    float4 o0, o1;
    o0.x = acc[i][0]+bias[0]; o0.y = acc[i][1]+bias[1];
    o0.z = acc[i][2]+bias[2]; o0.w = acc[i][3]+bias[3];
    o1.x = acc[i][4]+bias[4]; o1.y = acc[i][5]+bias[5];
    o1.z = acc[i][6]+bias[6]; o1.w = acc[i][7]+bias[7];
    *(float4*)(crow + n0 + tx*8)     = o0;
    *(float4*)(crow + n0 + tx*8 + 4) = o1;
  }
}

// ---------- split-bf16 MFMA final GEMM (validated R8) ----------
__global__ __launch_bounds__(256) void k_gemm_mfma(
    const float* __restrict__ A,   // Tops [2048][1024]
    const float* __restrict__ W,   // Wd [1024][32000]
    const float* __restrict__ bd,  // [32000]
    float* __restrict__ C)         // out [2048][32000]
{
  __shared__ unsigned short AsH[16*1024], AsL[16*1024];
  __shared__ unsigned short BsH[8*1024],  BsL[8*1024];
  int tid = threadIdx.x;
  int m0 = blockIdx.y*256, n0 = blockIdx.x*128;
  int w = tid >> 6, l = tid & 63;
  int lrow = l & 15, kg = l >> 4;

  f32x4 acc[4][8];
  #pragma unroll
  for (int i=0;i<4;i++){
    #pragma unroll
    for (int j=0;j<8;j++) acc[i][j] = (f32x4){0.f,0.f,0.f,0.f};
  }

  int rA  = tid >> 3, fq = tid & 7;

  for (int kt=0; kt<32; ++kt){
    int k0 = kt*32;
    float4 av[8];
    #pragma unroll
    for (int i=0;i<8;i++)
      av[i] = *(const float4*)(A + (size_t)(m0 + rA + 32*i)*1024 + k0 + fq*4);
    float4 wv[4];
    #pragma unroll
    for (int i=0;i<4;i++)
      wv[i] = *(const float4*)(W + (size_t)(k0 + rA)*VOC + n0 + fq*4 + 32*i);
    __syncthreads();
    #pragma unroll
    for (int i=0;i<8;i++){
      int r = rA + 32*i;
      int base = (r >> 4)*1024 + ((fq >> 1)*16 + (r & 15))*8 + (fq & 1)*4;
      float xs[4] = {av[i].x, av[i].y, av[i].z, av[i].w};
      unsigned long long ph = 0ull, pl = 0ull;
      #pragma unroll
      for (int c=0;c<4;c++){
        unsigned short h = f2bf(xs[c]);
        unsigned short lo = f2bf(xs[c] - bf2f(h));
        ph |= ((unsigned long long)h) << (16*c);
        pl |= ((unsigned long long)lo) << (16*c);
      }
      *(unsigned long long*)&AsH[base] = ph;
      *(unsigned long long*)&AsL[base] = pl;
    }
    #pragma unroll
    for (int i=0;i<4;i++){
      float xs[4] = {wv[i].x, wv[i].y, wv[i].z, wv[i].w};
      #pragma unroll
      for (int c=0;c<4;c++){
        int col = fq*4 + 32*i + c;
        int idx = (col >> 4)*1024 + ((rA >> 3)*16 + (col & 15))*8 + (rA & 7);
        unsigned short h = f2bf(xs[c]);
        BsH[idx] = h;
        BsL[idx] = f2bf(xs[c] - bf2f(h));
      }
    }
    __syncthreads();
    bf16x8 ah[4], al[4];
    #pragma unroll
    for (int i=0;i<4;i++){
      int fi = w*4 + i;
      ah[i] = *(const bf16x8*)&AsH[fi*1024 + l*8];
      al[i] = *(const bf16x8*)&AsL[fi*1024 + l*8];
    }
    #pragma unroll
    for (int jh=0;jh<2;jh++){
      bf16x8 bh[4], bl[4];
      #pragma unroll
      for (int j=0;j<4;j++){
        bh[j] = *(const bf16x8*)&BsH[(jh*4+j)*1024 + l*8];
        bl[j] = *(const bf16x8*)&BsL[(jh*4+j)*1024 + l*8];
      }
      #pragma unroll
      for (int i=0;i<4;i++){
        #pragma unroll
        for (int j=0;j<4;j++){
          f32x4 a = acc[i][jh*4+j];
          a = __builtin_amdgcn_mfma_f32_16x16x32_bf16(ah[i], bh[j], a, 0,0,0);
          a = __builtin_amdgcn_mfma_f32_16x16x32_bf16(ah[i], bl[j], a, 0,0,0);
          a = __builtin_amdgcn_mfma_f32_16x16x32_bf16(al[i], bh[j], a, 0,0,0);
          acc[i][jh*4+j] = a;
        }
      }
    }
    __syncthreads();
  }

  int mbase = m0 + w*64 + kg*4;
  #pragma unroll
  for (int jj=0;jj<8;jj++){
    int gn = n0 + jj*16 + lrow;
    float bias = bd[gn];
    #pragma unroll
    for (int i=0;i<4;i++){
      #pragma unroll
      for (int r=0;r<4;r++){
        int m = mbase + i*16 + r;
        int crow = (m & 7)*SEQ + (m >> 3);
        C[(size_t)crow*VOC + gn] = acc[i][jj][r] + bias;
      }
    }
  }
}

// ---------- persistent recurrence v8: epoch-fused dataflow (no barrier) ----------
// Each h element is a 64-bit {f32 h (lo), u32 epoch (hi)} word.
// Publish: ONE relaxed 64-bit atomic_exchange per element (RMW executes at the
//   coherence point; data+epoch arrive atomically -> no vmcnt, no flag, no fence).
// Consume: sc0/sc1-bypass float4 loads (2 pairs each); retry while any epoch
//   != t. The stage loop IS the synchronization (pure dataflow).
// Safety (parity reuse): block A publishes h_{t+2} into parity t only after A
//   staged ALL h_{t+1}, which requires every block published t+1, which happens
//   only after that block STAGED h_t -> no consumer of h_t can still need the
//   slot. Exact epoch match rejects stale (init=0) values.
__global__ __launch_bounds__(256) void k_rec(
    const float* __restrict__ G,
    const float* __restrict__ WhT,
    float* __restrict__ Hout,              // [2048][1024], row = t*8+b
    unsigned long long* __restrict__ hb2)  // [2][8][1024] {h,epoch}
{
  extern __shared__ float lds[];
  float* Wl  = lds;            // [16][1028]
  float* hl  = lds + 16448;    // [8][1028]
  float* gsc = lds + 24672;    // [4][64][2]
  int tid = threadIdx.x;
  int u0 = blockIdx.x*4;

  // one-time: stage 16 gate columns (c = gate*4+unit) into LDS
  {
    int c = tid >> 4, ks = tid & 15;
    const float* src = WhT + ((size_t)(c>>2)*1024 + u0 + (c&3))*1024 + ks*64;
    float* dst = Wl + c*1028 + ks*64;
    #pragma unroll
    for (int i=0;i<16;i++)
      *(float4*)(dst + i*4) = *(const float4*)(src + i*4);
  }

  const int wv = tid >> 6, ln = tid & 63;
  const int db = ln >> 3, dc = ln & 7;         // dot roles
  const int kbase = wv*256;
  const int sb = tid & 7, sk = (tid >> 3)*32;  // staging roles: 32 pairs/thread
  const int cb = tid >> 2, cj = tid & 3;       // cell roles (tid<32)
  float creg = 0.0f;

  for (int t=0;t<SEQ;t++){
    // ---- stage h_t with fused epoch check (retry until fresh) ----
    {
      const float* src = (const float*)(hb2 + (size_t)(t&1)*8192 + sb*1024 + sk);
      float4 q0,q1,q2,q3,q4,q5,q6,q7,q8,q9,qa,qb,qc,qd,qe,qf;
      unsigned tgt = (unsigned)t;
      int spins = 0;
      for (;;){
        asm volatile(
          "global_load_dwordx4 %0, %16, off sc0 sc1\n\t"
          "global_load_dwordx4 %1, %16, off offset:16 sc0 sc1\n\t"
          "global_load_dwordx4 %2, %16, off offset:32 sc0 sc1\n\t"
          "global_load_dwordx4 %3, %16, off offset:48 sc0 sc1\n\t"
          "global_load_dwordx4 %4, %16, off offset:64 sc0 sc1\n\t"
          "global_load_dwordx4 %5, %16, off offset:80 sc0 sc1\n\t"
          "global_load_dwordx4 %6, %16, off offset:96 sc0 sc1\n\t"
          "global_load_dwordx4 %7, %16, off offset:112 sc0 sc1\n\t"
          "global_load_dwordx4 %8, %16, off offset:128 sc0 sc1\n\t"
          "global_load_dwordx4 %9, %16, off offset:144 sc0 sc1\n\t"
          "global_load_dwordx4 %10, %16, off offset:160 sc0 sc1\n\t"
          "global_load_dwordx4 %11, %16, off offset:176 sc0 sc1\n\t"
          "global_load_dwordx4 %12, %16, off offset:192 sc0 sc1\n\t"
          "global_load_dwordx4 %13, %16, off offset:208 sc0 sc1\n\t"
          "global_load_dwordx4 %14, %16, off offset:224 sc0 sc1\n\t"
          "global_load_dwordx4 %15, %16, off offset:240 sc0 sc1\n\t"
          "s_waitcnt vmcnt(0)"
          : "=&v"(q0),"=&v"(q1),"=&v"(q2),"=&v"(q3),
            "=&v"(q4),"=&v"(q5),"=&v"(q6),"=&v"(q7),
            "=&v"(q8),"=&v"(q9),"=&v"(qa),"=&v"(qb),
            "=&v"(qc),"=&v"(qd),"=&v"(qe),"=&v"(qf)
          : "v"(src)
          : "memory");
        bool ok = (__float_as_uint(q0.y)==tgt) & (__float_as_uint(q0.w)==tgt)
                & (__float_as_uint(q1.y)==tgt) & (__float_as_uint(q1.w)==tgt)
                & (__float_as_uint(q2.y)==tgt) & (__float_as_uint(q2.w)==tgt)
                & (__float_as_uint(q3.y)==tgt) & (__float_as_uint(q3.w)==tgt)
                & (__float_as_uint(q4.y)==tgt) & (__float_as_uint(q4.w)==tgt)
                & (__float_as_uint(q5.y)==tgt) & (__float_as_uint(q5.w)==tgt)
                & (__float_as_uint(q6.y)==tgt) & (__float_as_uint(q6.w)==tgt)
                & (__float_as_uint(q7.y)==tgt) & (__float_as_uint(q7.w)==tgt)
                & (__float_as_uint(q8.y)==tgt) & (__float_as_uint(q8.w)==tgt)
                & (__float_as_uint(q9.y)==tgt) & (__float_as_uint(q9.w)==tgt)
                & (__float_as_uint(qa.y)==tgt) & (__float_as_uint(qa.w)==tgt)
                & (__float_as_uint(qb.y)==tgt) & (__float_as_uint(qb.w)==tgt)
                & (__float_as_uint(qc.y)==tgt) & (__float_as_uint(qc.w)==tgt)
                & (__float_as_uint(qd.y)==tgt) & (__float_as_uint(qd.w)==tgt)
                & (__float_as_uint(qe.y)==tgt) & (__float_as_uint(qe.w)==tgt)
                & (__float_as_uint(qf.y)==tgt) & (__float_as_uint(qf.w)==tgt);
        if (ok) break;
        if (++spins > 300000) break;   // safety valve: wrong answer beats a hang
        __builtin_amdgcn_s_sleep(1);
      }
      float* dst = hl + sb*1028 + sk;
      dst[ 0]=q0.x; dst[ 1]=q0.z; dst[ 2]=q1.x; dst[ 3]=q1.z;
      dst[ 4]=q2.x; dst[ 5]=q2.z; dst[ 6]=q3.x; dst[ 7]=q3.z;
      dst[ 8]=q4.x; dst[ 9]=q4.z; dst[10]=q5.x; dst[11]=q5.z;
      dst[12]=q6.x; dst[13]=q6.z; dst[14]=q7.x; dst[15]=q7.z;
      dst[16]=q8.x; dst[17]=q8.z; dst[18]=q9.x; dst[19]=q9.z;
      dst[20]=qa.x; dst[21]=qa.z; dst[22]=qb.x; dst[23]=qb.z;
      dst[24]=qc.x; dst[25]=qc.z; dst[26]=qd.x; dst[27]=qd.z;
      dst[28]=qe.x; dst[29]=qe.z; dst[30]=qf.x; dst[31]=qf.z;
    }
    // prefetch x-gate pre-activations (plain cached loads; G read-only)
    float gp0=0.f,gp1=0.f,gp2=0.f,gp3=0.f;
    if (tid < 32){
      const float* gp = G + ((size_t)t*8 + cb)*GATES + u0 + cj;
      gp0 = gp[0]; gp1 = gp[1024]; gp2 = gp[2048]; gp3 = gp[3072];
    }
    __syncthreads();

    // dot: cols dc and dc+8 for batch db over K [kbase, kbase+256)
    float a0 = 0.f, a1 = 0.f;
    const float* hp = hl + db*1028 + kbase;
    const float* w0 = Wl + dc*1028 + kbase;
    const float* w1 = Wl + (dc+8)*1028 + kbase;
    #pragma unroll 4
    for (int k=0;k<256;k+=4){
      float4 hv = *(const float4*)(hp + k);
      float4 x0 = *(const float4*)(w0 + k);
      float4 x1 = *(const float4*)(w1 + k);
      a0 = fmaf(hv.x,x0.x,a0); a0 = fmaf(hv.y,x0.y,a0);
      a0 = fmaf(hv.z,x0.z,a0); a0 = fmaf(hv.w,x0.w,a0);
      a1 = fmaf(hv.x,x1.x,a1); a1 = fmaf(hv.y,x1.y,a1);
      a1 = fmaf(hv.z,x1.z,a1); a1 = fmaf(hv.w,x1.w,a1);
    }
    gsc[wv*128 + ln*2 + 0] = a0;
    gsc[wv*128 + ln*2 + 1] = a1;
    __syncthreads();

    // cell update + fused publish (tid<32)
    if (tid < 32){
      int b0 = (cb*8 + cj)*2, b1i = (cb*8 + 4 + cj)*2;
      float xi = gp0, xf = gp1, xg = gp2, xo = gp3;
      #pragma unroll
      for (int w=0;w<4;w++){
        xi += gsc[w*128 + b0];
        xf += gsc[w*128 + b1i];
        xg += gsc[w*128 + b0 + 1];
        xo += gsc[w*128 + b1i + 1];
      }
      float iv = sigf(xi), fv = sigf(xf), ov = sigf(xo), gv = tanhf_(xg);
      creg = fv*creg + iv*gv;
      float hv = ov * tanhf_(creg);
      if (t < SEQ-1){
        unsigned long long pk = ((unsigned long long)(unsigned)(t+1) << 32)
                              | (unsigned long long)__float_as_uint(hv);
        (void)__hip_atomic_exchange(&hb2[(size_t)((t+1)&1)*8192 + cb*1024 + u0 + cj],
                                    pk, __ATOMIC_RELAXED, __HIP_MEMORY_SCOPE_AGENT);
      }
      Hout[((size_t)t*8 + cb)*HID + u0 + cj] = hv;
    }
    // no grid barrier: next iteration's stage retries until epochs arrive
  }
}

extern "C" void kernel_launch(void* const* d_in, const int* in_sizes, int n_in,
                              void* d_out, int out_size, void* d_ws, size_t ws_size,
                              hipStream_t stream) {
  const int*   tokens = (const int*)d_in[0];
  const float* emb = (const float*)d_in[1];
  const float* Wx  = (const float*)d_in[2];
  const float* bx  = (const float*)d_in[3];
  const float* Wh  = (const float*)d_in[4];
  const float* bh  = (const float*)d_in[5];
  const float* Wd  = (const float*)d_in[6];
  const float* bd  = (const float*)d_in[7];
  float* out = (float*)d_out;
  float* ws  = (float*)d_ws;

  // ws layout (floats): G 8388608 | H0 2097152 | Tops 2097152 | WhT 8388608 |
  //                     hb2 65536 (2 layers x 2 x 8192 x 8B)
  float* G    = ws;
  float* H0   = ws + (size_t)8388608;
  float* Tops = ws + (size_t)10485760;
  float* WhT  = ws + (size_t)12582912;
  unsigned long long* hb2 = (unsigned long long*)(ws + (size_t)20971520);

  (void)hipFuncSetAttribute((const void*)k_rec,
        hipFuncAttributeMaxDynamicSharedMemorySize, 101376);

  k_init<<<32,256,0,stream>>>(hb2);
  k_transpose<<<dim3(128,32,2), dim3(32,8), 0, stream>>>(Wh, WhT);

  // layer 0: G0 = emb[tok] @ Wx0 + (bx0+bh0)
  k_gemm<1><<<dim3(32,16),256,0,stream>>>(nullptr, Wx, bx, bh, tokens, emb, G, GATES);
  k_rec<<<256,256,101376,stream>>>(G, WhT, H0, hb2);

  // layer 1: G1 = H0 @ Wx1 + (bx1+bh1)
  k_gemm<0><<<dim3(32,16),256,0,stream>>>(H0, Wx + (size_t)1024*GATES, bx+GATES, bh+GATES,
                                          nullptr, nullptr, G, GATES);
  k_rec<<<256,256,101376,stream>>>(G, WhT + (size_t)GATES*HID, Tops, hb2 + 16384);

  // final projection (split-bf16 MFMA): out[b][t][v] = Tops[t*8+b] @ Wd + bd
  k_gemm_mfma<<<dim3(250,8),256,0,stream>>>(Tops, Wd, bd, out);
}

// Round 10
// 4789.861 us; speedup vs baseline: 2.3203x; 2.3203x over previous
//
#include <hip/hip_runtime.h>
#include <cstdint>
#include <cstddef>

#define BATCH 8
#define SEQ   256
#define HID   1024
#define GATES 4096   // 4*HID
#define VOC   32000

typedef __attribute__((ext_vector_type(8))) short bf16x8;
typedef __attribute__((ext_vector_type(4))) float f32x4;

// ---------- helpers ----------
__device__ __forceinline__ float sigf(float x){ return 1.0f/(1.0f + __expf(-x)); }
__device__ __forceinline__ float tanhf_(float x){ return 1.0f - 2.0f/(__expf(2.0f*x) + 1.0f); }

__device__ __forceinline__ unsigned short f2bf(float x){
  union { float f; unsigned u; } v; v.f = x;
  unsigned r = v.u + 0x7fffu + ((v.u >> 16) & 1u);
  return (unsigned short)(r >> 16);
}
__device__ __forceinline__ float bf2f(unsigned short h){
  union { float f; unsigned u; } v; v.u = ((unsigned)h) << 16; return v.f;
}

// ---------- init: zero epoch flags + h ping-pong buffers ----------
__global__ void k_init(unsigned* __restrict__ flags, float* __restrict__ hb){
  int tid = blockIdx.x*blockDim.x + threadIdx.x;
  int nt = gridDim.x*blockDim.x;
  for (int i = tid; i < 2*256*16; i += nt) flags[i] = 0u;
  for (int i = tid; i < 2*2*BATCH*HID; i += nt) hb[i] = 0.0f;
}

// ---------- Wh transpose: WhT[l][n][k] = Wh[l][k][n] ----------
__global__ void k_transpose(const float* __restrict__ Wh, float* __restrict__ WhT){
  __shared__ float tile[32][33];
  int l = blockIdx.z;
  int n0 = blockIdx.x*32, k0 = blockIdx.y*32;
  const float* src = Wh  + (size_t)l*HID*GATES;
  float*       dst = WhT + (size_t)l*GATES*HID;
  int tx = threadIdx.x, ty = threadIdx.y;
  #pragma unroll
  for (int i=0;i<4;i++)
    tile[ty+i*8][tx] = src[(size_t)(k0+ty+i*8)*GATES + n0 + tx];
  __syncthreads();
  #pragma unroll
  for (int i=0;i<4;i++)
    dst[(size_t)(n0+ty+i*8)*HID + k0 + tx] = tile[tx][ty+i*8];
}

// ---------- split-bf16 MFMA GEMM (R8-validated structure, unified) ----------
// C = A@W + b1 (+ b2), computed as Ah*Wh + Ah*Wl + Al*Wh. K fixed 1024.
// Tile 256xB128, BK=32, 4 waves. AMODE 1: A-row gm = emb[tokens[(gm&7)*SEQ+(gm>>3)]].
// OMODE 1: out row = (m&7)*SEQ + (m>>3) (B,T permute); else row = m.
template<int AMODE, int OMODE>
__global__ __launch_bounds__(256) void k_mfma(
    const float* __restrict__ A,
    const float* __restrict__ W,     // [1024][N]
    const float* __restrict__ b1,
    const float* __restrict__ b2,
    const int*   __restrict__ tokens,
    const float* __restrict__ emb,
    float* __restrict__ C, int N)
{
  __shared__ unsigned short AsH[16*1024], AsL[16*1024];
  __shared__ unsigned short BsH[8*1024],  BsL[8*1024];
  int tid = threadIdx.x;
  int m0 = blockIdx.y*256, n0 = blockIdx.x*128;
  int w = tid >> 6, l = tid & 63;
  int lrow = l & 15, kg = l >> 4;

  f32x4 acc[4][8];
  #pragma unroll
  for (int i=0;i<4;i++){
    #pragma unroll
    for (int j=0;j<8;j++) acc[i][j] = (f32x4){0.f,0.f,0.f,0.f};
  }

  int rA  = tid >> 3, fq = tid & 7;   // staging roles: 8 threads/row

  // hoist A row pointers (gather once)
  const float* arow[8];
  #pragma unroll
  for (int i=0;i<8;i++){
    int gm = m0 + rA + 32*i;
    if (AMODE==1) arow[i] = emb + (size_t)tokens[(gm&7)*SEQ + (gm>>3)]*1024;
    else          arow[i] = A   + (size_t)gm*1024;
  }

  for (int kt=0; kt<32; ++kt){
    int k0 = kt*32;
    float4 av[8];
    #pragma unroll
    for (int i=0;i<8;i++)
      av[i] = *(const float4*)(arow[i] + k0 + fq*4);
    float4 wv[4];
    #pragma unroll
    for (int i=0;i<4;i++)
      wv[i] = *(const float4*)(W + (size_t)(k0 + rA)*N + n0 + fq*4 + 32*i);
    __syncthreads();
    #pragma unroll
    for (int i=0;i<8;i++){
      int r = rA + 32*i;
      int base = (r >> 4)*1024 + ((fq >> 1)*16 + (r & 15))*8 + (fq & 1)*4;
      float xs[4] = {av[i].x, av[i].y, av[i].z, av[i].w};
      unsigned long long ph = 0ull, pl = 0ull;
      #pragma unroll
      for (int c=0;c<4;c++){
        unsigned short h = f2bf(xs[c]);
        unsigned short lo = f2bf(xs[c] - bf2f(h));
        ph |= ((unsigned long long)h) << (16*c);
        pl |= ((unsigned long long)lo) << (16*c);
      }
      *(unsigned long long*)&AsH[base] = ph;
      *(unsigned long long*)&AsL[base] = pl;
    }
    #pragma unroll
    for (int i=0;i<4;i++){
      float xs[4] = {wv[i].x, wv[i].y, wv[i].z, wv[i].w};
      #pragma unroll
      for (int c=0;c<4;c++){
        int col = fq*4 + 32*i + c;
        int idx = (col >> 4)*1024 + ((rA >> 3)*16 + (col & 15))*8 + (rA & 7);
        unsigned short h = f2bf(xs[c]);
        BsH[idx] = h;
        BsL[idx] = f2bf(xs[c] - bf2f(h));
      }
    }
    __syncthreads();
    bf16x8 ah[4], al[4];
    #pragma unroll
    for (int i=0;i<4;i++){
      int fi = w*4 + i;
      ah[i] = *(const bf16x8*)&AsH[fi*1024 + l*8];
      al[i] = *(const bf16x8*)&AsL[fi*1024 + l*8];
    }
    #pragma unroll
    for (int jh=0;jh<2;jh++){
      bf16x8 bh[4], bl[4];
      #pragma unroll
      for (int j=0;j<4;j++){
        bh[j] = *(const bf16x8*)&BsH[(jh*4+j)*1024 + l*8];
        bl[j] = *(const bf16x8*)&BsL[(jh*4+j)*1024 + l*8];
      }
      #pragma unroll
      for (int i=0;i<4;i++){
        #pragma unroll
        for (int j=0;j<4;j++){
          f32x4 a = acc[i][jh*4+j];
          a = __builtin_amdgcn_mfma_f32_16x16x32_bf16(ah[i], bh[j], a, 0,0,0);
          a = __builtin_amdgcn_mfma_f32_16x16x32_bf16(ah[i], bl[j], a, 0,0,0);
          a = __builtin_amdgcn_mfma_f32_16x16x32_bf16(al[i], bh[j], a, 0,0,0);
          acc[i][jh*4+j] = a;
        }
      }
    }
    __syncthreads();
  }

  int mbase = m0 + w*64 + kg*4;
  #pragma unroll
  for (int jj=0;jj<8;jj++){
    int gn = n0 + jj*16 + lrow;
    float bias = b1[gn];
    if (b2) bias += b2[gn];
    #pragma unroll
    for (int i=0;i<4;i++){
      #pragma unroll
      for (int r=0;r<4;r++){
        int m = mbase + i*16 + r;
        size_t crow = (OMODE==1) ? (size_t)((m & 7)*SEQ + (m >> 3)) : (size_t)m;
        C[crow*(size_t)N + gn] = acc[i][jj][r] + bias;
      }
    }
  }
}

// ---------- persistent recurrence v7 (proven; reverted verbatim from R8) ----------
__global__ __launch_bounds__(256) void k_rec(
    const float* __restrict__ G,
    const float* __restrict__ WhT,
    float* __restrict__ Hout,        // [2048][1024], row = t*8+b
    unsigned* __restrict__ hb,       // ping-pong [2][8][1024] as uint bits
    unsigned* __restrict__ flags)    // [256][16] epoch slots
{
  extern __shared__ float lds[];
  float* Wl  = lds;            // [16][1028]
  float* hl  = lds + 16448;    // [8][1028]
  float* gsc = lds + 24672;    // [4][64][2]
  int tid = threadIdx.x;
  int u0 = blockIdx.x*4;

  {
    int c = tid >> 4, ks = tid & 15;
    const float* src = WhT + ((size_t)(c>>2)*1024 + u0 + (c&3))*1024 + ks*64;
    float* dst = Wl + c*1028 + ks*64;
    #pragma unroll
    for (int i=0;i<16;i++)
      *(float4*)(dst + i*4) = *(const float4*)(src + i*4);
  }

  const int wv = tid >> 6, ln = tid & 63;
  const int db = ln >> 3, dc = ln & 7;
  const int kbase = wv*256;
  const int sb = tid & 7, sk = (tid >> 3)*32;
  const int cb = tid >> 2, cj = tid & 3;
  const int fs0 = tid*16, fs1 = (tid+64)*16, fs2 = (tid+128)*16, fs3 = (tid+192)*16;
  float creg = 0.0f;

  for (int t=0;t<SEQ;t++){
    {
      const float* src = (const float*)(hb + (t&1)*8192) + sb*1024 + sk;
      float4 r0,r1,r2,r3,r4,r5,r6,r7;
      asm volatile(
        "global_load_dwordx4 %0, %8, off sc0 sc1\n\t"
        "global_load_dwordx4 %1, %8, off offset:16 sc0 sc1\n\t"
        "global_load_dwordx4 %2, %8, off offset:32 sc0 sc1\n\t"
        "global_load_dwordx4 %3, %8, off offset:48 sc0 sc1\n\t"
        "global_load_dwordx4 %4, %8, off offset:64 sc0 sc1\n\t"
        "global_load_dwordx4 %5, %8, off offset:80 sc0 sc1\n\t"
        "global_load_dwordx4 %6, %8, off offset:96 sc0 sc1\n\t"
        "global_load_dwordx4 %7, %8, off offset:112 sc0 sc1\n\t"
        "s_waitcnt vmcnt(0)"
        : "=&v"(r0),"=&v"(r1),"=&v"(r2),"=&v"(r3),
          "=&v"(r4),"=&v"(r5),"=&v"(r6),"=&v"(r7)
        : "v"(src)
        : "memory");
      float* dst = hl + sb*1028 + sk;
      *(float4*)(dst+ 0)=r0; *(float4*)(dst+ 4)=r1;
      *(float4*)(dst+ 8)=r2; *(float4*)(dst+12)=r3;
      *(float4*)(dst+16)=r4; *(float4*)(dst+20)=r5;
      *(float4*)(dst+24)=r6; *(float4*)(dst+28)=r7;
    }
    float gp0=0.f,gp1=0.f,gp2=0.f,gp3=0.f;
    if (tid < 32){
      const float* gp = G + ((size_t)t*8 + cb)*GATES + u0 + cj;
      gp0 = gp[0]; gp1 = gp[1024]; gp2 = gp[2048]; gp3 = gp[3072];
    }
    __syncthreads();

    float a0 = 0.f, a1 = 0.f;
    const float* hp = hl + db*1028 + kbase;
    const float* w0 = Wl + dc*1028 + kbase;
    const float* w1 = Wl + (dc+8)*1028 + kbase;
    #pragma unroll 4
    for (int k=0;k<256;k+=4){
      float4 hv = *(const float4*)(hp + k);
      float4 x0 = *(const float4*)(w0 + k);
      float4 x1 = *(const float4*)(w1 + k);
      a0 = fmaf(hv.x,x0.x,a0); a0 = fmaf(hv.y,x0.y,a0);
      a0 = fmaf(hv.z,x0.z,a0); a0 = fmaf(hv.w,x0.w,a0);
      a1 = fmaf(hv.x,x1.x,a1); a1 = fmaf(hv.y,x1.y,a1);
      a1 = fmaf(hv.z,x1.z,a1); a1 = fmaf(hv.w,x1.w,a1);
    }
    gsc[wv*128 + ln*2 + 0] = a0;
    gsc[wv*128 + ln*2 + 1] = a1;
    __syncthreads();

    if (tid < 32){
      int b0 = (cb*8 + cj)*2, b1i = (cb*8 + 4 + cj)*2;
      float xi = gp0, xf = gp1, xg = gp2, xo = gp3;
      #pragma unroll
      for (int w=0;w<4;w++){
        xi += gsc[w*128 + b0];
        xf += gsc[w*128 + b1i];
        xg += gsc[w*128 + b0 + 1];
        xo += gsc[w*128 + b1i + 1];
      }
      float iv = sigf(xi), fv = sigf(xf), ov = sigf(xo), gv = tanhf_(xg);
      creg = fv*creg + iv*gv;
      float hv = ov * tanhf_(creg);
      if (t < SEQ-1){
        (void)__hip_atomic_exchange(&hb[((t+1)&1)*8192 + cb*1024 + u0 + cj],
                                    __float_as_uint(hv), __ATOMIC_RELAXED,
                                    __HIP_MEMORY_SCOPE_AGENT);
      }
      Hout[((size_t)t*8 + cb)*HID + u0 + cj] = hv;
    }

    if (t < SEQ-1){
      if (tid < 64){
        if (tid == 0){
          asm volatile("s_waitcnt vmcnt(0)" ::: "memory");
          (void)__hip_atomic_exchange(&flags[blockIdx.x*16], (unsigned)(t+1),
                                      __ATOMIC_RELAXED, __HIP_MEMORY_SCOPE_AGENT);
        }
        unsigned tgt = (unsigned)(t+1);
        int spins = 0;
        for (;;){
          unsigned a = __hip_atomic_load(&flags[fs0], __ATOMIC_RELAXED, __HIP_MEMORY_SCOPE_AGENT);
          unsigned b = __hip_atomic_load(&flags[fs1], __ATOMIC_RELAXED, __HIP_MEMORY_SCOPE_AGENT);
          unsigned c = __hip_atomic_load(&flags[fs2], __ATOMIC_RELAXED, __HIP_MEMORY_SCOPE_AGENT);
          unsigned d = __hip_atomic_load(&flags[fs3], __ATOMIC_RELAXED, __HIP_MEMORY_SCOPE_AGENT);
          bool ok = (a >= tgt) && (b >= tgt) && (c >= tgt) && (d >= tgt);
          if (__all(ok)) break;
          __builtin_amdgcn_s_sleep(1);
          if (++spins > 150000){
            for (;;){
              unsigned a2 = __hip_atomic_load(&flags[fs0], __ATOMIC_ACQUIRE, __HIP_MEMORY_SCOPE_AGENT);
              unsigned b2 = __hip_atomic_load(&flags[fs1], __ATOMIC_ACQUIRE, __HIP_MEMORY_SCOPE_AGENT);
              unsigned c2 = __hip_atomic_load(&flags[fs2], __ATOMIC_ACQUIRE, __HIP_MEMORY_SCOPE_AGENT);
              unsigned d2 = __hip_atomic_load(&flags[fs3], __ATOMIC_ACQUIRE, __HIP_MEMORY_SCOPE_AGENT);
              bool ok2 = (a2 >= tgt) && (b2 >= tgt) && (c2 >= tgt) && (d2 >= tgt);
              if (__all(ok2)) break;
              __builtin_amdgcn_s_sleep(8);
              if (++spins > 8000000) break;
            }
            break;
          }
        }
      }
      __syncthreads();
    }
  }
}

extern "C" void kernel_launch(void* const* d_in, const int* in_sizes, int n_in,
                              void* d_out, int out_size, void* d_ws, size_t ws_size,
                              hipStream_t stream) {
  const int*   tokens = (const int*)d_in[0];
  const float* emb = (const float*)d_in[1];
  const float* Wx  = (const float*)d_in[2];
  const float* bx  = (const float*)d_in[3];
  const float* Wh  = (const float*)d_in[4];
  const float* bh  = (const float*)d_in[5];
  const float* Wd  = (const float*)d_in[6];
  const float* bd  = (const float*)d_in[7];
  float* out = (float*)d_out;
  float* ws  = (float*)d_ws;

  // ws layout (floats): G 8388608 | H0 2097152 | Tops 2097152 | WhT 8388608 |
  //                     hb 32768 (2 layers x 2 x 8192) | flags 8192 (2 x 4096)
  float* G    = ws;
  float* H0   = ws + (size_t)8388608;
  float* Tops = ws + (size_t)10485760;
  float* WhT  = ws + (size_t)12582912;
  unsigned* hb    = (unsigned*)(ws + (size_t)20971520);
  unsigned* flags = (unsigned*)(ws + (size_t)21004288);

  (void)hipFuncSetAttribute((const void*)k_rec,
        hipFuncAttributeMaxDynamicSharedMemorySize, 101376);

  k_init<<<32,256,0,stream>>>(flags, (float*)hb);
  k_transpose<<<dim3(128,32,2), dim3(32,8), 0, stream>>>(Wh, WhT);

  // layer 0: G0 = emb[tok] @ Wx0 + (bx0+bh0)   [split-bf16 MFMA]
  k_mfma<1,0><<<dim3(32,8),256,0,stream>>>(nullptr, Wx, bx, bh, tokens, emb, G, GATES);
  k_rec<<<256,256,101376,stream>>>(G, WhT, H0, hb, flags);

  // layer 1: G1 = H0 @ Wx1 + (bx1+bh1)   [split-bf16 MFMA]
  k_mfma<0,0><<<dim3(32,8),256,0,stream>>>(H0, Wx + (size_t)1024*GATES, bx+GATES, bh+GATES,
                                           nullptr, nullptr, G, GATES);
  k_rec<<<256,256,101376,stream>>>(G, WhT + (size_t)GATES*HID, Tops,
                                   hb + 16384, flags + 4096);

  // final projection (split-bf16 MFMA): out[b][t][v] = Tops[t*8+b] @ Wd + bd
  k_mfma<0,1><<<dim3(250,8),256,0,stream>>>(Tops, Wd, bd, nullptr, nullptr, nullptr, out, VOC);
}

// Round 11
// 3699.991 us; speedup vs baseline: 3.0037x; 1.2946x over previous
//
#include <hip/hip_runtime.h>
#include <cstdint>
#include <cstddef>

#define BATCH 8
#define SEQ   256
#define HID   1024
#define GATES 4096   // 4*HID
#define VOC   32000

typedef __attribute__((ext_vector_type(8))) short bf16x8;
typedef __attribute__((ext_vector_type(4))) float f32x4;

// ---------- helpers ----------
__device__ __forceinline__ float sigf(float x){ return 1.0f/(1.0f + __expf(-x)); }
__device__ __forceinline__ float tanhf_(float x){ return 1.0f - 2.0f/(__expf(2.0f*x) + 1.0f); }

__device__ __forceinline__ unsigned short f2bf(float x){
  union { float f; unsigned u; } v; v.f = x;
  unsigned r = v.u + 0x7fffu + ((v.u >> 16) & 1u);
  return (unsigned short)(r >> 16);
}
__device__ __forceinline__ float bf2f(unsigned short h){
  union { float f; unsigned u; } v; v.u = ((unsigned)h) << 16; return v.f;
}

// ---------- init: zero epoch flags + h state buffers ----------
__global__ void k_init(unsigned* __restrict__ flags, float* __restrict__ hb){
  int tid = blockIdx.x*blockDim.x + threadIdx.x;
  int nt = gridDim.x*blockDim.x;
  for (int i = tid; i < 256*16; i += nt) flags[i] = 0u;
  for (int i = tid; i < 2*2*BATCH*HID; i += nt) hb[i] = 0.0f;
}

// ---------- split-bf16 MFMA GEMM (R8/R10-validated) ----------
template<int AMODE, int OMODE>
__global__ __launch_bounds__(256) void k_mfma(
    const float* __restrict__ A,
    const float* __restrict__ W,     // [1024][N]
    const float* __restrict__ b1,
    const float* __restrict__ b2,
    const int*   __restrict__ tokens,
    const float* __restrict__ emb,
    float* __restrict__ C, int N)
{
  __shared__ unsigned short AsH[16*1024], AsL[16*1024];
  __shared__ unsigned short BsH[8*1024],  BsL[8*1024];
  int tid = threadIdx.x;
  int m0 = blockIdx.y*256, n0 = blockIdx.x*128;
  int w = tid >> 6, l = tid & 63;
  int lrow = l & 15, kg = l >> 4;

  f32x4 acc[4][8];
  #pragma unroll
  for (int i=0;i<4;i++){
    #pragma unroll
    for (int j=0;j<8;j++) acc[i][j] = (f32x4){0.f,0.f,0.f,0.f};
  }

  int rA  = tid >> 3, fq = tid & 7;

  const float* arow[8];
  #pragma unroll
  for (int i=0;i<8;i++){
    int gm = m0 + rA + 32*i;
    if (AMODE==1) arow[i] = emb + (size_t)tokens[(gm&7)*SEQ + (gm>>3)]*1024;
    else          arow[i] = A   + (size_t)gm*1024;
  }

  for (int kt=0; kt<32; ++kt){
    int k0 = kt*32;
    float4 av[8];
    #pragma unroll
    for (int i=0;i<8;i++)
      av[i] = *(const float4*)(arow[i] + k0 + fq*4);
    float4 wv[4];
    #pragma unroll
    for (int i=0;i<4;i++)
      wv[i] = *(const float4*)(W + (size_t)(k0 + rA)*N + n0 + fq*4 + 32*i);
    __syncthreads();
    #pragma unroll
    for (int i=0;i<8;i++){
      int r = rA + 32*i;
      int base = (r >> 4)*1024 + ((fq >> 1)*16 + (r & 15))*8 + (fq & 1)*4;
      float xs[4] = {av[i].x, av[i].y, av[i].z, av[i].w};
      unsigned long long ph = 0ull, pl = 0ull;
      #pragma unroll
      for (int c=0;c<4;c++){
        unsigned short h = f2bf(xs[c]);
        unsigned short lo = f2bf(xs[c] - bf2f(h));
        ph |= ((unsigned long long)h) << (16*c);
        pl |= ((unsigned long long)lo) << (16*c);
      }
      *(unsigned long long*)&AsH[base] = ph;
      *(unsigned long long*)&AsL[base] = pl;
    }
    #pragma unroll
    for (int i=0;i<4;i++){
      float xs[4] = {wv[i].x, wv[i].y, wv[i].z, wv[i].w};
      #pragma unroll
      for (int c=0;c<4;c++){
        int col = fq*4 + 32*i + c;
        int idx = (col >> 4)*1024 + ((rA >> 3)*16 + (col & 15))*8 + (rA & 7);
        unsigned short h = f2bf(xs[c]);
        BsH[idx] = h;
        BsL[idx] = f2bf(xs[c] - bf2f(h));
      }
    }
    __syncthreads();
    bf16x8 ah[4], al[4];
    #pragma unroll
    for (int i=0;i<4;i++){
      int fi = w*4 + i;
      ah[i] = *(const bf16x8*)&AsH[fi*1024 + l*8];
      al[i] = *(const bf16x8*)&AsL[fi*1024 + l*8];
    }
    #pragma unroll
    for (int jh=0;jh<2;jh++){
      bf16x8 bh_[4], bl_[4];
      #pragma unroll
      for (int j=0;j<4;j++){
        bh_[j] = *(const bf16x8*)&BsH[(jh*4+j)*1024 + l*8];
        bl_[j] = *(const bf16x8*)&BsL[(jh*4+j)*1024 + l*8];
      }
      #pragma unroll
      for (int i=0;i<4;i++){
        #pragma unroll
        for (int j=0;j<4;j++){
          f32x4 a = acc[i][jh*4+j];
          a = __builtin_amdgcn_mfma_f32_16x16x32_bf16(ah[i], bh_[j], a, 0,0,0);
          a = __builtin_amdgcn_mfma_f32_16x16x32_bf16(ah[i], bl_[j], a, 0,0,0);
          a = __builtin_amdgcn_mfma_f32_16x16x32_bf16(al[i], bh_[j], a, 0,0,0);
          acc[i][jh*4+j] = a;
        }
      }
    }
    __syncthreads();
  }

  int mbase = m0 + w*64 + kg*4;
  #pragma unroll
  for (int jj=0;jj<8;jj++){
    int gn = n0 + jj*16 + lrow;
    float bias = b1[gn];
    if (b2) bias += b2[gn];
    #pragma unroll
    for (int i=0;i<4;i++){
      #pragma unroll
      for (int r=0;r<4;r++){
        int m = mbase + i*16 + r;
        size_t crow = (OMODE==1) ? (size_t)((m & 7)*SEQ + (m >> 3)) : (size_t)m;
        C[crow*(size_t)N + gn] = acc[i][jj][r] + bias;
      }
    }
  }
}

// ---------- fused 2-layer pipelined recurrence (v9) ----------
// 257 phases; phase p: L0 step p (consumes state0(p), G0[p]) and L1 step p-1
// (consumes state0(p) as x-input + state1(p-1)). All three per-phase GEMVs are
// MFMA 16x16x32 on ONE shared B-tile: cols 0-7 = h0(bf16), cols 8-15 = h1.
//   C0 = Wh0@B (use cols0-7), C1 = Wx1@B (cols0-7), C2 = Wh1@B (cols8-15);
//   gates1[m][b] = C1[m][b] + C2[m][b+8] + bias1.
// Weights: single-bf16 frag-linear A-tiles in LDS (static). h transport = v7's
// proven MALL path (f32 swaps + per-block flag + relaxed poll, no fences).
// LDS: A0|A1|A2|hB 4x32768B @0 + Cx [4][3][16][17] f32 @131072 = 144128 B.
__global__ __launch_bounds__(256) void k_rec2(
    const float* __restrict__ G,      // G0 [2048][4096], bias folded
    const float* __restrict__ Wh,     // [2][1024][4096]
    const float* __restrict__ Wx,     // [2][1024][4096]
    const float* __restrict__ bx1,    // bx + GATES
    const float* __restrict__ bh1,    // bh + GATES
    float* __restrict__ Tops,         // [2048][1024], row = s*8+b
    unsigned* __restrict__ hbu,       // [st0:2x8192][st1:2x8192] f32 bits
    unsigned* __restrict__ flags)     // [256][16]
{
  extern __shared__ char ldsb[];
  unsigned short* A0 = (unsigned short*)ldsb;
  unsigned short* A1 = A0 + 16384;
  unsigned short* A2 = A1 + 16384;
  unsigned short* hB = A2 + 16384;
  float* Cx = (float*)(ldsb + 131072);   // [(w*3+acc)*16 + m][17] + col
  int tid = threadIdx.x;
  int u0 = blockIdx.x*4;
  const int wv = tid >> 6, ln = tid & 63;
  const int fs0 = tid*16, fs1 = (tid+64)*16, fs2 = (tid+128)*16, fs3 = (tid+192)*16;

  // one-time: stage 3 weight A-tiles (bf16 frag-linear), strided reads
  {
    int m = tid >> 4, kseg = tid & 15;
    int col = (m >> 2)*1024 + u0 + (m & 3);   // gate*1024 + unit
    const float* wsrc[3] = { Wh, Wx + (size_t)HID*GATES, Wh + (size_t)HID*GATES };
    unsigned short* Ad[3] = { A0, A1, A2 };
    for (int tgt=0; tgt<3; ++tgt){
      const float* s = wsrc[tgt] + col;
      #pragma unroll
      for (int run=0; run<8; ++run){
        int k0 = kseg*64 + run*8;
        int kt = k0 >> 5, kg = (k0 >> 3) & 3;
        bf16x8 v;
        #pragma unroll
        for (int e=0;e<8;e++) v[e] = (short)f2bf(s[(size_t)(k0+e)*GATES]);
        *(bf16x8*)&Ad[tgt][kt*512 + ((kg<<4)|m)*8] = v;
      }
    }
  }
  float b1r[4] = {0.f,0.f,0.f,0.f};
  if (tid >= 32 && tid < 64){
    int j = tid & 3;
    #pragma unroll
    for (int g=0;g<4;g++) b1r[g] = bx1[g*1024+u0+j] + bh1[g*1024+u0+j];
  }
  float creg = 0.0f;

  for (int p=0; p<=SEQ; ++p){
    // ---- stage B-tile: h0 = state0(p) [buf0 parity p&1], h1 = state1(p-1) [buf1 parity (p+1)&1]
    const float* h0b = (const float*)(hbu + (size_t)(p&1)*8192);
    const float* h1b = (const float*)(hbu + 16384 + (size_t)((p+1)&1)*8192);
    {
      int colp = tid & 15, seg0 = tid >> 4;
      #pragma unroll
      for (int i=0;i<2;i++){
        int seg = seg0 + 16*i;                 // = kt, 32 consecutive k
        const float* src = ((colp < 8) ? h0b : h1b) + (colp & 7)*1024 + seg*32;
        float4 r0,r1,r2,r3,r4,r5,r6,r7;
        asm volatile(
          "global_load_dwordx4 %0, %8, off sc0 sc1\n\t"
          "global_load_dwordx4 %1, %8, off offset:16 sc0 sc1\n\t"
          "global_load_dwordx4 %2, %8, off offset:32 sc0 sc1\n\t"
          "global_load_dwordx4 %3, %8, off offset:48 sc0 sc1\n\t"
          "global_load_dwordx4 %4, %8, off offset:64 sc0 sc1\n\t"
          "global_load_dwordx4 %5, %8, off offset:80 sc0 sc1\n\t"
          "global_load_dwordx4 %6, %8, off offset:96 sc0 sc1\n\t"
          "global_load_dwordx4 %7, %8, off offset:112 sc0 sc1\n\t"
          "s_waitcnt vmcnt(0)"
          : "=&v"(r0),"=&v"(r1),"=&v"(r2),"=&v"(r3),
            "=&v"(r4),"=&v"(r5),"=&v"(r6),"=&v"(r7)
          : "v"(src)
          : "memory");
        float vals[32] = {r0.x,r0.y,r0.z,r0.w, r1.x,r1.y,r1.z,r1.w,
                          r2.x,r2.y,r2.z,r2.w, r3.x,r3.y,r3.z,r3.w,
                          r4.x,r4.y,r4.z,r4.w, r5.x,r5.y,r5.z,r5.w,
                          r6.x,r6.y,r6.z,r6.w, r7.x,r7.y,r7.z,r7.w};
        #pragma unroll
        for (int kg=0;kg<4;kg++){
          bf16x8 v;
          #pragma unroll
          for (int e=0;e<8;e++) v[e] = (short)f2bf(vals[kg*8+e]);
          *(bf16x8*)&hB[seg*512 + ((kg<<4)|colp)*8] = v;
        }
      }
    }
    // G0 prefetch for L0 cell lanes
    float gp0=0.f,gp1=0.f,gp2=0.f,gp3=0.f;
    if (tid < 32 && p < SEQ){
      const float* gp = G + ((size_t)p*8 + (tid>>2))*GATES + u0 + (tid&3);
      gp0 = gp[0]; gp1 = gp[1024]; gp2 = gp[2048]; gp3 = gp[3072];
    }
    __syncthreads();

    // ---- MFMA: 3 products share B-tile; waves split kt-space
    f32x4 C0 = {0.f,0.f,0.f,0.f}, C1 = {0.f,0.f,0.f,0.f}, C2 = {0.f,0.f,0.f,0.f};
    #pragma unroll
    for (int kti=0; kti<8; ++kti){
      int kt = wv + kti*4;
      bf16x8 bB = *(const bf16x8*)&hB[kt*512 + ln*8];
      bf16x8 a0 = *(const bf16x8*)&A0[kt*512 + ln*8];
      bf16x8 a1 = *(const bf16x8*)&A1[kt*512 + ln*8];
      bf16x8 a2 = *(const bf16x8*)&A2[kt*512 + ln*8];
      C0 = __builtin_amdgcn_mfma_f32_16x16x32_bf16(a0, bB, C0, 0,0,0);
      C1 = __builtin_amdgcn_mfma_f32_16x16x32_bf16(a1, bB, C1, 0,0,0);
      C2 = __builtin_amdgcn_mfma_f32_16x16x32_bf16(a2, bB, C2, 0,0,0);
    }
    {
      int cn = ln & 15, mb = (ln >> 4)*4;
      #pragma unroll
      for (int r=0;r<4;r++){
        Cx[((wv*3+0)*16 + mb+r)*17 + cn] = C0[r];
        Cx[((wv*3+1)*16 + mb+r)*17 + cn] = C1[r];
        Cx[((wv*3+2)*16 + mb+r)*17 + cn] = C2[r];
      }
    }
    __syncthreads();

    // ---- cells + publish (wave 0: lanes 0-31 = L0, 32-63 = L1)
    if (tid < 32){
      if (p < SEQ){
        int b = tid >> 2, j = tid & 3;
        float gv0=gp0, gv1=gp1, gv2=gp2, gv3=gp3;
        #pragma unroll
        for (int w=0;w<4;w++){
          gv0 += Cx[((w*3+0)*16 + 0*4+j)*17 + b];
          gv1 += Cx[((w*3+0)*16 + 1*4+j)*17 + b];
          gv2 += Cx[((w*3+0)*16 + 2*4+j)*17 + b];
          gv3 += Cx[((w*3+0)*16 + 3*4+j)*17 + b];
        }
        float iv = sigf(gv0), fv = sigf(gv1), ov = sigf(gv3), gg = tanhf_(gv2);
        creg = fv*creg + iv*gg;
        float hv = ov * tanhf_(creg);
        (void)__hip_atomic_exchange(&hbu[(size_t)((p+1)&1)*8192 + b*1024 + u0 + j],
                                    __float_as_uint(hv), __ATOMIC_RELAXED,
                                    __HIP_MEMORY_SCOPE_AGENT);
      }
    } else if (tid < 64){
      if (p > 0){
        int b = (tid-32) >> 2, j = tid & 3;
        float gv0=b1r[0], gv1=b1r[1], gv2=b1r[2], gv3=b1r[3];
        #pragma unroll
        for (int w=0;w<4;w++){
          gv0 += Cx[((w*3+1)*16 + 0*4+j)*17 + b] + Cx[((w*3+2)*16 + 0*4+j)*17 + b+8];
          gv1 += Cx[((w*3+1)*16 + 1*4+j)*17 + b] + Cx[((w*3+2)*16 + 1*4+j)*17 + b+8];
          gv2 += Cx[((w*3+1)*16 + 2*4+j)*17 + b] + Cx[((w*3+2)*16 + 2*4+j)*17 + b+8];
          gv3 += Cx[((w*3+1)*16 + 3*4+j)*17 + b] + Cx[((w*3+2)*16 + 3*4+j)*17 + b+8];
        }
        float iv = sigf(gv0), fv = sigf(gv1), ov = sigf(gv3), gg = tanhf_(gv2);
        creg = fv*creg + iv*gg;
        float hv = ov * tanhf_(creg);
        (void)__hip_atomic_exchange(&hbu[16384 + (size_t)(p&1)*8192 + b*1024 + u0 + j],
                                    __float_as_uint(hv), __ATOMIC_RELAXED,
                                    __HIP_MEMORY_SCOPE_AGENT);
        Tops[((size_t)(p-1)*8 + b)*HID + u0 + j] = hv;
      }
    }

    // ---- flag + poll (skip after final phase)
    if (p < SEQ){
      if (tid < 64){
        if (tid == 0){
          asm volatile("s_waitcnt vmcnt(0)" ::: "memory");
          (void)__hip_atomic_exchange(&flags[blockIdx.x*16], (unsigned)(p+1),
                                      __ATOMIC_RELAXED, __HIP_MEMORY_SCOPE_AGENT);
        }
        unsigned tgt = (unsigned)(p+1);
        int spins = 0;
        for (;;){
          unsigned a = __hip_atomic_load(&flags[fs0], __ATOMIC_RELAXED, __HIP_MEMORY_SCOPE_AGENT);
          unsigned b = __hip_atomic_load(&flags[fs1], __ATOMIC_RELAXED, __HIP_MEMORY_SCOPE_AGENT);
          unsigned c = __hip_atomic_load(&flags[fs2], __ATOMIC_RELAXED, __HIP_MEMORY_SCOPE_AGENT);
          unsigned d = __hip_atomic_load(&flags[fs3], __ATOMIC_RELAXED, __HIP_MEMORY_SCOPE_AGENT);
          bool ok = (a >= tgt) && (b >= tgt) && (c >= tgt) && (d >= tgt);
          if (__all(ok)) break;
          __builtin_amdgcn_s_sleep(1);
          if (++spins > 150000){
            for (;;){
              unsigned a2 = __hip_atomic_load(&flags[fs0], __ATOMIC_ACQUIRE, __HIP_MEMORY_SCOPE_AGENT);
              unsigned b2 = __hip_atomic_load(&flags[fs1], __ATOMIC_ACQUIRE, __HIP_MEMORY_SCOPE_AGENT);
              unsigned c2 = __hip_atomic_load(&flags[fs2], __ATOMIC_ACQUIRE, __HIP_MEMORY_SCOPE_AGENT);
              unsigned d2 = __hip_atomic_load(&flags[fs3], __ATOMIC_ACQUIRE, __HIP_MEMORY_SCOPE_AGENT);
              bool ok2 = (a2 >= tgt) && (b2 >= tgt) && (c2 >= tgt) && (d2 >= tgt);
              if (__all(ok2)) break;
              __builtin_amdgcn_s_sleep(8);
              if (++spins > 8000000) break;   // wrong answer beats a hang
            }
            break;
          }
        }
      }
      __syncthreads();
    }
  }
}

extern "C" void kernel_launch(void* const* d_in, const int* in_sizes, int n_in,
                              void* d_out, int out_size, void* d_ws, size_t ws_size,
                              hipStream_t stream) {
  const int*   tokens = (const int*)d_in[0];
  const float* emb = (const float*)d_in[1];
  const float* Wx  = (const float*)d_in[2];
  const float* bx  = (const float*)d_in[3];
  const float* Wh  = (const float*)d_in[4];
  const float* bh  = (const float*)d_in[5];
  const float* Wd  = (const float*)d_in[6];
  const float* bd  = (const float*)d_in[7];
  float* out = (float*)d_out;
  float* ws  = (float*)d_ws;

  // ws layout (floats): G 8388608 | Tops 2097152 | hbu 32768 | flags 4096
  float* G    = ws;
  float* Tops = ws + (size_t)8388608;
  unsigned* hbu   = (unsigned*)(ws + (size_t)10485760);
  unsigned* flags = (unsigned*)(ws + (size_t)10518528);

  (void)hipFuncSetAttribute((const void*)k_rec2,
        hipFuncAttributeMaxDynamicSharedMemorySize, 144128);

  k_init<<<32,256,0,stream>>>(flags, (float*)hbu);

  // G0 = emb[tok] @ Wx0 + (bx0+bh0)   [split-bf16 MFMA]
  k_mfma<1,0><<<dim3(32,8),256,0,stream>>>(nullptr, Wx, bx, bh, tokens, emb, G, GATES);

  // fused pipelined recurrence: both layers, 257 phases
  k_rec2<<<256,256,144128,stream>>>(G, Wh, Wx, bx + GATES, bh + GATES,
                                    Tops, hbu, flags);

  // final projection (split-bf16 MFMA): out[b][t][v] = Tops[t*8+b] @ Wd + bd
  k_mfma<0,1><<<dim3(250,8),256,0,stream>>>(Tops, Wd, bd, nullptr, nullptr, nullptr, out, VOC);
}

// Round 12
// 2109.037 us; speedup vs baseline: 5.2696x; 1.7544x over previous
//
#include <hip/hip_runtime.h>
#include <cstdint>
#include <cstddef>

#define BATCH 8
#define SEQ   256
#define HID   1024
#define GATES 4096   // 4*HID
#define VOC   32000

typedef __attribute__((ext_vector_type(8))) short bf16x8;
typedef __attribute__((ext_vector_type(4))) float f32x4;

// ---------- helpers ----------
__device__ __forceinline__ float sigf(float x){ return 1.0f/(1.0f + __expf(-x)); }
__device__ __forceinline__ float tanhf_(float x){ return 1.0f - 2.0f/(__expf(2.0f*x) + 1.0f); }

__device__ __forceinline__ unsigned short f2bf(float x){
  union { float f; unsigned u; } v; v.f = x;
  unsigned r = v.u + 0x7fffu + ((v.u >> 16) & 1u);
  return (unsigned short)(r >> 16);
}
__device__ __forceinline__ float bf2f(unsigned short h){
  union { float f; unsigned u; } v; v.u = ((unsigned)h) << 16; return v.f;
}

// ---------- init: zero epoch flags + packed h buffers ----------
// hbu: [2 layers][2 parity][8 cols][512 u32] = 16384 u32 (2xbf16 per word)
__global__ void k_init(unsigned* __restrict__ flags, unsigned* __restrict__ hbu){
  int tid = blockIdx.x*blockDim.x + threadIdx.x;
  int nt = gridDim.x*blockDim.x;
  for (int i = tid; i < 256*16; i += nt) flags[i] = 0u;
  for (int i = tid; i < 16384; i += nt) hbu[i] = 0u;
}

// ---------- split-bf16 MFMA GEMM (R8/R10-validated) ----------
template<int AMODE, int OMODE>
__global__ __launch_bounds__(256) void k_mfma(
    const float* __restrict__ A,
    const float* __restrict__ W,     // [1024][N]
    const float* __restrict__ b1,
    const float* __restrict__ b2,
    const int*   __restrict__ tokens,
    const float* __restrict__ emb,
    float* __restrict__ C, int N)
{
  __shared__ unsigned short AsH[16*1024], AsL[16*1024];
  __shared__ unsigned short BsH[8*1024],  BsL[8*1024];
  int tid = threadIdx.x;
  int m0 = blockIdx.y*256, n0 = blockIdx.x*128;
  int w = tid >> 6, l = tid & 63;
  int lrow = l & 15, kg = l >> 4;

  f32x4 acc[4][8];
  #pragma unroll
  for (int i=0;i<4;i++){
    #pragma unroll
    for (int j=0;j<8;j++) acc[i][j] = (f32x4){0.f,0.f,0.f,0.f};
  }

  int rA  = tid >> 3, fq = tid & 7;

  const float* arow[8];
  #pragma unroll
  for (int i=0;i<8;i++){
    int gm = m0 + rA + 32*i;
    if (AMODE==1) arow[i] = emb + (size_t)tokens[(gm&7)*SEQ + (gm>>3)]*1024;
    else          arow[i] = A   + (size_t)gm*1024;
  }

  for (int kt=0; kt<32; ++kt){
    int k0 = kt*32;
    float4 av[8];
    #pragma unroll
    for (int i=0;i<8;i++)
      av[i] = *(const float4*)(arow[i] + k0 + fq*4);
    float4 wv[4];
    #pragma unroll
    for (int i=0;i<4;i++)
      wv[i] = *(const float4*)(W + (size_t)(k0 + rA)*N + n0 + fq*4 + 32*i);
    __syncthreads();
    #pragma unroll
    for (int i=0;i<8;i++){
      int r = rA + 32*i;
      int base = (r >> 4)*1024 + ((fq >> 1)*16 + (r & 15))*8 + (fq & 1)*4;
      float xs[4] = {av[i].x, av[i].y, av[i].z, av[i].w};
      unsigned long long ph = 0ull, pl = 0ull;
      #pragma unroll
      for (int c=0;c<4;c++){
        unsigned short h = f2bf(xs[c]);
        unsigned short lo = f2bf(xs[c] - bf2f(h));
        ph |= ((unsigned long long)h) << (16*c);
        pl |= ((unsigned long long)lo) << (16*c);
      }
      *(unsigned long long*)&AsH[base] = ph;
      *(unsigned long long*)&AsL[base] = pl;
    }
    #pragma unroll
    for (int i=0;i<4;i++){
      float xs[4] = {wv[i].x, wv[i].y, wv[i].z, wv[i].w};
      #pragma unroll
      for (int c=0;c<4;c++){
        int col = fq*4 + 32*i + c;
        int idx = (col >> 4)*1024 + ((rA >> 3)*16 + (col & 15))*8 + (rA & 7);
        unsigned short h = f2bf(xs[c]);
        BsH[idx] = h;
        BsL[idx] = f2bf(xs[c] - bf2f(h));
      }
    }
    __syncthreads();
    bf16x8 ah[4], al[4];
    #pragma unroll
    for (int i=0;i<4;i++){
      int fi = w*4 + i;
      ah[i] = *(const bf16x8*)&AsH[fi*1024 + l*8];
      al[i] = *(const bf16x8*)&AsL[fi*1024 + l*8];
    }
    #pragma unroll
    for (int jh=0;jh<2;jh++){
      bf16x8 bh_[4], bl_[4];
      #pragma unroll
      for (int j=0;j<4;j++){
        bh_[j] = *(const bf16x8*)&BsH[(jh*4+j)*1024 + l*8];
        bl_[j] = *(const bf16x8*)&BsL[(jh*4+j)*1024 + l*8];
      }
      #pragma unroll
      for (int i=0;i<4;i++){
        #pragma unroll
        for (int j=0;j<4;j++){
          f32x4 a = acc[i][jh*4+j];
          a = __builtin_amdgcn_mfma_f32_16x16x32_bf16(ah[i], bh_[j], a, 0,0,0);
          a = __builtin_amdgcn_mfma_f32_16x16x32_bf16(ah[i], bl_[j], a, 0,0,0);
          a = __builtin_amdgcn_mfma_f32_16x16x32_bf16(al[i], bh_[j], a, 0,0,0);
          acc[i][jh*4+j] = a;
        }
      }
    }
    __syncthreads();
  }

  int mbase = m0 + w*64 + kg*4;
  #pragma unroll
  for (int jj=0;jj<8;jj++){
    int gn = n0 + jj*16 + lrow;
    float bias = b1[gn];
    if (b2) bias += b2[gn];
    #pragma unroll
    for (int i=0;i<4;i++){
      #pragma unroll
      for (int r=0;r<4;r++){
        int m = mbase + i*16 + r;
        size_t crow = (OMODE==1) ? (size_t)((m & 7)*SEQ + (m >> 3)) : (size_t)m;
        C[crow*(size_t)N + gn] = acc[i][jj][r] + bias;
      }
    }
  }
}

// ---------- fused 2-layer pipelined recurrence (v10: bf16-packed transport) ----------
// Same 257-phase pipeline as v9 (R11). Change: h transported as packed 2xbf16
// per u32 word (h only ever consumed as bf16 B-tile; Tops written f32 separately
// -> bit-identical results). Producer packs via __shfl_xor(1) (wave-0-uniform),
// publishes 32 relaxed exchanges/block; stager is a pure bit-copy: 4x dwordx4
// sc0/sc1 + 4 contiguous float4 LDS stores per thread. No conversions.
// hbu layout: [2 layers][2 parity][8 cols][512 u32]; word w of col b = units {2w, 2w+1}.
__global__ __launch_bounds__(256) void k_rec2(
    const float* __restrict__ G,      // G0 [2048][4096], bias folded
    const float* __restrict__ Wh,     // [2][1024][4096]
    const float* __restrict__ Wx,     // [2][1024][4096]
    const float* __restrict__ bx1,    // bx + GATES
    const float* __restrict__ bh1,    // bh + GATES
    float* __restrict__ Tops,         // [2048][1024], row = s*8+b
    unsigned* __restrict__ hbu,       // packed h (see above)
    unsigned* __restrict__ flags)     // [256][16]
{
  extern __shared__ char ldsb[];
  unsigned short* A0 = (unsigned short*)ldsb;
  unsigned short* A1 = A0 + 16384;
  unsigned short* A2 = A1 + 16384;
  unsigned short* hB = A2 + 16384;
  float* Cx = (float*)(ldsb + 131072);   // [(w*3+acc)*16 + m][17] + col
  int tid = threadIdx.x;
  int u0 = blockIdx.x*4;
  const int wv = tid >> 6, ln = tid & 63;
  const int fs0 = tid*16, fs1 = (tid+64)*16, fs2 = (tid+128)*16, fs3 = (tid+192)*16;

  // one-time: stage 3 weight A-tiles (bf16 frag-linear), strided reads
  {
    int m = tid >> 4, kseg = tid & 15;
    int col = (m >> 2)*1024 + u0 + (m & 3);   // gate*1024 + unit
    const float* wsrc[3] = { Wh, Wx + (size_t)HID*GATES, Wh + (size_t)HID*GATES };
    unsigned short* Ad[3] = { A0, A1, A2 };
    for (int tgt=0; tgt<3; ++tgt){
      const float* s = wsrc[tgt] + col;
      #pragma unroll
      for (int run=0; run<8; ++run){
        int k0 = kseg*64 + run*8;
        int kt = k0 >> 5, kg = (k0 >> 3) & 3;
        bf16x8 v;
        #pragma unroll
        for (int e=0;e<8;e++) v[e] = (short)f2bf(s[(size_t)(k0+e)*GATES]);
        *(bf16x8*)&Ad[tgt][kt*512 + ((kg<<4)|m)*8] = v;
      }
    }
  }
  float b1r[4] = {0.f,0.f,0.f,0.f};
  if (tid >= 32 && tid < 64){
    int j = tid & 3;
    #pragma unroll
    for (int g=0;g<4;g++) b1r[g] = bx1[g*1024+u0+j] + bh1[g*1024+u0+j];
  }
  float creg = 0.0f;

  for (int p=0; p<=SEQ; ++p){
    // ---- stage B-tile (bit-copy): h0 = state0(p) parity p&1; h1 = state1(p-1) parity (p+1)&1
    const unsigned* h0b = hbu + (size_t)(p&1)*4096;
    const unsigned* h1b = hbu + 8192 + (size_t)((p+1)&1)*4096;
    {
      int colp = tid & 15, seg0 = tid >> 4;
      #pragma unroll
      for (int i=0;i<2;i++){
        int seg = seg0 + 16*i;                 // = kt
        const float* src = (const float*)(((colp < 8) ? h0b : h1b)
                                          + (colp & 7)*512 + seg*16);
        float4 r0,r1,r2,r3;
        asm volatile(
          "global_load_dwordx4 %0, %4, off sc0 sc1\n\t"
          "global_load_dwordx4 %1, %4, off offset:16 sc0 sc1\n\t"
          "global_load_dwordx4 %2, %4, off offset:32 sc0 sc1\n\t"
          "global_load_dwordx4 %3, %4, off offset:48 sc0 sc1\n\t"
          "s_waitcnt vmcnt(0)"
          : "=&v"(r0),"=&v"(r1),"=&v"(r2),"=&v"(r3)
          : "v"(src)
          : "memory");
        *(float4*)&hB[seg*512 + ((0<<4)|colp)*8] = r0;
        *(float4*)&hB[seg*512 + ((1<<4)|colp)*8] = r1;
        *(float4*)&hB[seg*512 + ((2<<4)|colp)*8] = r2;
        *(float4*)&hB[seg*512 + ((3<<4)|colp)*8] = r3;
      }
    }
    // G0 prefetch for L0 cell lanes
    float gp0=0.f,gp1=0.f,gp2=0.f,gp3=0.f;
    if (tid < 32 && p < SEQ){
      const float* gp = G + ((size_t)p*8 + (tid>>2))*GATES + u0 + (tid&3);
      gp0 = gp[0]; gp1 = gp[1024]; gp2 = gp[2048]; gp3 = gp[3072];
    }
    __syncthreads();

    // ---- MFMA: 3 products share B-tile; waves split kt-space
    f32x4 C0 = {0.f,0.f,0.f,0.f}, C1 = {0.f,0.f,0.f,0.f}, C2 = {0.f,0.f,0.f,0.f};
    #pragma unroll
    for (int kti=0; kti<8; ++kti){
      int kt = wv + kti*4;
      bf16x8 bB = *(const bf16x8*)&hB[kt*512 + ln*8];
      bf16x8 a0 = *(const bf16x8*)&A0[kt*512 + ln*8];
      bf16x8 a1 = *(const bf16x8*)&A1[kt*512 + ln*8];
      bf16x8 a2 = *(const bf16x8*)&A2[kt*512 + ln*8];
      C0 = __builtin_amdgcn_mfma_f32_16x16x32_bf16(a0, bB, C0, 0,0,0);
      C1 = __builtin_amdgcn_mfma_f32_16x16x32_bf16(a1, bB, C1, 0,0,0);
      C2 = __builtin_amdgcn_mfma_f32_16x16x32_bf16(a2, bB, C2, 0,0,0);
    }
    {
      int cn = ln & 15, mb = (ln >> 4)*4;
      #pragma unroll
      for (int r=0;r<4;r++){
        Cx[((wv*3+0)*16 + mb+r)*17 + cn] = C0[r];
        Cx[((wv*3+1)*16 + mb+r)*17 + cn] = C1[r];
        Cx[((wv*3+2)*16 + mb+r)*17 + cn] = C2[r];
      }
    }
    __syncthreads();

    // ---- cells (wave 0: lanes 0-31 = L0, 32-63 = L1), then packed publish
    float hv = 0.f; bool pub = false; unsigned dstbase = 0;
    if (tid < 32){
      if (p < SEQ){
        int b = tid >> 2, j = tid & 3;
        float gv0=gp0, gv1=gp1, gv2=gp2, gv3=gp3;
        #pragma unroll
        for (int w=0;w<4;w++){
          gv0 += Cx[((w*3+0)*16 + 0*4+j)*17 + b];
          gv1 += Cx[((w*3+0)*16 + 1*4+j)*17 + b];
          gv2 += Cx[((w*3+0)*16 + 2*4+j)*17 + b];
          gv3 += Cx[((w*3+0)*16 + 3*4+j)*17 + b];
        }
        float iv = sigf(gv0), fv = sigf(gv1), ov = sigf(gv3), gg = tanhf_(gv2);
        creg = fv*creg + iv*gg;
        hv = ov * tanhf_(creg);
        pub = true; dstbase = ((unsigned)(p+1)&1u)*4096u;
      }
    } else if (tid < 64){
      if (p > 0){
        int b = (tid-32) >> 2, j = tid & 3;
        float gv0=b1r[0], gv1=b1r[1], gv2=b1r[2], gv3=b1r[3];
        #pragma unroll
        for (int w=0;w<4;w++){
          gv0 += Cx[((w*3+1)*16 + 0*4+j)*17 + b] + Cx[((w*3+2)*16 + 0*4+j)*17 + b+8];
          gv1 += Cx[((w*3+1)*16 + 1*4+j)*17 + b] + Cx[((w*3+2)*16 + 1*4+j)*17 + b+8];
          gv2 += Cx[((w*3+1)*16 + 2*4+j)*17 + b] + Cx[((w*3+2)*16 + 2*4+j)*17 + b+8];
          gv3 += Cx[((w*3+1)*16 + 3*4+j)*17 + b] + Cx[((w*3+2)*16 + 3*4+j)*17 + b+8];
        }
        float iv = sigf(gv0), fv = sigf(gv1), ov = sigf(gv3), gg = tanhf_(gv2);
        creg = fv*creg + iv*gg;
        hv = ov * tanhf_(creg);
        pub = true; dstbase = 8192u + ((unsigned)p&1u)*4096u;
        Tops[((size_t)(p-1)*8 + b)*HID + u0 + (tid&3)] = hv;
      }
    }
    if (tid < 64){
      // pack {even-j, odd-j} bf16 pair; shfl executed by ALL of wave 0 (no divergence)
      unsigned mybits = (unsigned)f2bf(hv);
      unsigned other  = (unsigned)__shfl_xor((int)mybits, 1);
      if (pub && ((tid & 1) == 0)){
        unsigned word = (mybits & 0xffffu) | (other << 16);
        int b = (tid & 31) >> 2;
        int widx = (u0 >> 1) + ((tid >> 1) & 1);
        (void)__hip_atomic_exchange(&hbu[dstbase + b*512 + widx], word,
                                    __ATOMIC_RELAXED, __HIP_MEMORY_SCOPE_AGENT);
      }
    }

    // ---- flag + poll (skip after final phase)
    if (p < SEQ){
      if (tid < 64){
        if (tid == 0){
          asm volatile("s_waitcnt vmcnt(0)" ::: "memory");  // wave-0 exchanges done at MALL
          (void)__hip_atomic_exchange(&flags[blockIdx.x*16], (unsigned)(p+1),
                                      __ATOMIC_RELAXED, __HIP_MEMORY_SCOPE_AGENT);
        }
        unsigned tgt = (unsigned)(p+1);
        int spins = 0;
        for (;;){
          unsigned a = __hip_atomic_load(&flags[fs0], __ATOMIC_RELAXED, __HIP_MEMORY_SCOPE_AGENT);
          unsigned b = __hip_atomic_load(&flags[fs1], __ATOMIC_RELAXED, __HIP_MEMORY_SCOPE_AGENT);
          unsigned c = __hip_atomic_load(&flags[fs2], __ATOMIC_RELAXED, __HIP_MEMORY_SCOPE_AGENT);
          unsigned d = __hip_atomic_load(&flags[fs3], __ATOMIC_RELAXED, __HIP_MEMORY_SCOPE_AGENT);
          bool ok = (a >= tgt) && (b >= tgt) && (c >= tgt) && (d >= tgt);
          if (__all(ok)) break;
          __builtin_amdgcn_s_sleep(1);
          if (++spins > 150000){
            for (;;){
              unsigned a2 = __hip_atomic_load(&flags[fs0], __ATOMIC_ACQUIRE, __HIP_MEMORY_SCOPE_AGENT);
              unsigned b2 = __hip_atomic_load(&flags[fs1], __ATOMIC_ACQUIRE, __HIP_MEMORY_SCOPE_AGENT);
              unsigned c2 = __hip_atomic_load(&flags[fs2], __ATOMIC_ACQUIRE, __HIP_MEMORY_SCOPE_AGENT);
              unsigned d2 = __hip_atomic_load(&flags[fs3], __ATOMIC_ACQUIRE, __HIP_MEMORY_SCOPE_AGENT);
              bool ok2 = (a2 >= tgt) && (b2 >= tgt) && (c2 >= tgt) && (d2 >= tgt);
              if (__all(ok2)) break;
              __builtin_amdgcn_s_sleep(8);
              if (++spins > 8000000) break;   // wrong answer beats a hang
            }
            break;
          }
        }
      }
      __syncthreads();
    }
  }
}

extern "C" void kernel_launch(void* const* d_in, const int* in_sizes, int n_in,
                              void* d_out, int out_size, void* d_ws, size_t ws_size,
                              hipStream_t stream) {
  const int*   tokens = (const int*)d_in[0];
  const float* emb = (const float*)d_in[1];
  const float* Wx  = (const float*)d_in[2];
  const float* bx  = (const float*)d_in[3];
  const float* Wh  = (const float*)d_in[4];
  const float* bh  = (const float*)d_in[5];
  const float* Wd  = (const float*)d_in[6];
  const float* bd  = (const float*)d_in[7];
  float* out = (float*)d_out;
  float* ws  = (float*)d_ws;

  // ws layout (floats): G 8388608 | Tops 2097152 | hbu 16384 | flags 4096
  float* G    = ws;
  float* Tops = ws + (size_t)8388608;
  unsigned* hbu   = (unsigned*)(ws + (size_t)10485760);
  unsigned* flags = (unsigned*)(ws + (size_t)10502144);

  (void)hipFuncSetAttribute((const void*)k_rec2,
        hipFuncAttributeMaxDynamicSharedMemorySize, 144128);

  k_init<<<32,256,0,stream>>>(flags, hbu);

  // G0 = emb[tok] @ Wx0 + (bx0+bh0)   [split-bf16 MFMA]
  k_mfma<1,0><<<dim3(32,8),256,0,stream>>>(nullptr, Wx, bx, bh, tokens, emb, G, GATES);

  // fused pipelined recurrence: both layers, 257 phases
  k_rec2<<<256,256,144128,stream>>>(G, Wh, Wx, bx + GATES, bh + GATES,
                                    Tops, hbu, flags);

  // final projection (split-bf16 MFMA): out[b][t][v] = Tops[t*8+b] @ Wd + bd
  k_mfma<0,1><<<dim3(250,8),256,0,stream>>>(Tops, Wd, bd, nullptr, nullptr, nullptr, out, VOC);
}